// Round 4
// baseline (85.359 us; speedup 1.0000x reference)
//
#include <hip/hip_runtime.h>
#include <math.h>

typedef __attribute__((ext_vector_type(4))) float f32x4;
typedef __attribute__((ext_vector_type(8))) short bf16x8;

#define NCLS  1000
#define DDIM  128
#define NB    65536
#define K2    14.426950408889634f   /* (1/T)*log2(e): base-2 logits */
#define LN2   0.6931471805599453f

__device__ inline short f2bf(float f) {
  union { float f; unsigned u; } x; x.f = f;
  unsigned r = (x.u + 0x7fffu + ((x.u >> 16) & 1u)) >> 16;  // RNE
  return (short)r;
}
__device__ inline void gll16(const void* g, void* l) {
  __builtin_amdgcn_global_load_lds(
      (const __attribute__((address_space(1))) unsigned int*)g,
      (__attribute__((address_space(3))) unsigned int*)l, 16, 0, 0);
}

// mu (f32 1000x128) -> bf16, FRAG-MAJOR layout, zero-padded to 1024 classes.
// Unit (c, ks, khi) -> byte (c>>7)*32768 + ((c>>4)&7)*4096 + ks*1024
//                      + (khi*16 + (c&15))*16
// so each MFMA B-fragment (16 cols x 32 k) is one contiguous, lane-linear 1KB.
__global__ __launch_bounds__(256) void prep_mu(const float* __restrict__ mu,
                                               short* __restrict__ mubf) {
  int idx = blockIdx.x * 256 + threadIdx.x;   // 64 blocks -> 16384 16B units
  int c = idx >> 4, j = idx & 15;
  int ks = j >> 2, khi = j & 3;
  bf16x8 o = {0, 0, 0, 0, 0, 0, 0, 0};
  if (c < NCLS) {
    const float4* p = reinterpret_cast<const float4*>(mu + (size_t)c * DDIM + ks * 32 + khi * 8);
    float4 u0 = p[0], u1 = p[1];
    o[0] = f2bf(u0.x); o[1] = f2bf(u0.y); o[2] = f2bf(u0.z); o[3] = f2bf(u0.w);
    o[4] = f2bf(u1.x); o[5] = f2bf(u1.y); o[6] = f2bf(u1.z); o[7] = f2bf(u1.w);
  }
  size_t a16 = (size_t)(c >> 7) * 2048 + ((c >> 4) & 7) * 256 + ks * 64 + khi * 16 + (c & 15);
  *reinterpret_cast<bf16x8*>(mubf + a16 * 8) = o;
}

// Compactness: 1024 blocks (512 row-bands x 2 col-halves) x 4 waves.
// Wave owns 32 rows x 512 cols. 32KB single-buffer LDS -> 4 blocks/CU,
// 16 waves/CU. Frag-major LDS: ds_read = base + lane*16 + imm (no conflicts).
__global__ __launch_bounds__(256, 4) void cider_comp(
    const float* __restrict__ z, const short* __restrict__ mubf,
    const int* __restrict__ tgt, float2* __restrict__ part,
    float* __restrict__ posarr) {
  const int tid = threadIdx.x;
  const int wid = tid >> 6, lane = tid & 63;
  const int lo = lane & 15, hi = lane >> 4;
  const int rb = blockIdx.x >> 1, half = blockIdx.x & 1;
  const int rowbase = rb * 128 + wid * 32;

  __shared__ __align__(16) char Bt[32768];
  const char* mb = (const char*)mubf;

  auto stage = [&](int cc) {   // chunk cc of this half: contiguous 32KB
    const char* src = mb + (size_t)(half * 4 + cc) * 32768 + wid * 8192 + lane * 16;
    char* dst = Bt + wid * 8192;
#pragma unroll
    for (int i = 0; i < 8; ++i) gll16(src + i * 1024, dst + i * 1024);
  };
  stage(0);

  // A fragments (scaled by K2) and targets
  bf16x8 a[2][4];
#pragma unroll
  for (int rt = 0; rt < 2; ++rt) {
    int row = rowbase + rt * 16 + lo;
    const float4* zp = reinterpret_cast<const float4*>(z + (size_t)row * DDIM);
#pragma unroll
    for (int ks = 0; ks < 4; ++ks) {
      float4 u0 = zp[ks * 8 + hi * 2];
      float4 u1 = zp[ks * 8 + hi * 2 + 1];
      bf16x8 s;
      s[0] = f2bf(u0.x * K2); s[1] = f2bf(u0.y * K2);
      s[2] = f2bf(u0.z * K2); s[3] = f2bf(u0.w * K2);
      s[4] = f2bf(u1.x * K2); s[5] = f2bf(u1.y * K2);
      s[6] = f2bf(u1.z * K2); s[7] = f2bf(u1.w * K2);
      a[rt][ks] = s;
    }
  }
  int t8[2][4];
#pragma unroll
  for (int rt = 0; rt < 2; ++rt)
#pragma unroll
    for (int r = 0; r < 4; ++r) t8[rt][r] = tgt[rowbase + rt * 16 + hi * 4 + r];

  float m2[2][4], s2[2][4], pos[2][4];
#pragma unroll
  for (int rt = 0; rt < 2; ++rt)
#pragma unroll
    for (int r = 0; r < 4; ++r) { m2[rt][r] = -1e30f; s2[rt][r] = 0.f; pos[rt][r] = -3.0e38f; }

#pragma unroll 1
  for (int cc = 0; cc < 4; ++cc) {
    __syncthreads();   // stage(cc) landed (barrier drains vmcnt)
    const int cb = half * 512 + cc * 128;
#pragma unroll
    for (int g = 0; g < 2; ++g) {
      f32x4 acc[2][4];
#pragma unroll
      for (int rt = 0; rt < 2; ++rt)
#pragma unroll
        for (int f = 0; f < 4; ++f) acc[rt][f] = f32x4{0.f, 0.f, 0.f, 0.f};
#pragma unroll
      for (int ks = 0; ks < 4; ++ks) {
#pragma unroll
        for (int f = 0; f < 4; ++f) {
          bf16x8 b = *reinterpret_cast<const bf16x8*>(
              Bt + ((g * 4 + f) * 4 + ks) * 1024 + lane * 16);
          acc[0][f] = __builtin_amdgcn_mfma_f32_16x16x32_bf16(a[0][ks], b, acc[0][f], 0, 0, 0);
          acc[1][f] = __builtin_amdgcn_mfma_f32_16x16x32_bf16(a[1][ks], b, acc[1][f], 0, 0, 0);
        }
      }
      const int colb = cb + g * 64 + lo;
#pragma unroll
      for (int rt = 0; rt < 2; ++rt)
#pragma unroll
        for (int r = 0; r < 4; ++r) {
          float l0 = acc[rt][0][r], l1 = acc[rt][1][r];
          float l2 = acc[rt][2][r], l3 = acc[rt][3][r];
          int t = t8[rt][r];
          float p = pos[rt][r];
          p = (colb == t) ? l0 : p;
          p = (colb + 16 == t) ? l1 : p;
          p = (colb + 32 == t) ? l2 : p;
          p = (colb + 48 == t) ? l3 : p;
          pos[rt][r] = p;
          float cm = fmaxf(fmaxf(l0, l1), fmaxf(l2, l3));
          float mo = m2[rt][r], mn = fmaxf(mo, cm);
          s2[rt][r] = s2[rt][r] * __builtin_amdgcn_exp2f(mo - mn)
                    + __builtin_amdgcn_exp2f(l0 - mn) + __builtin_amdgcn_exp2f(l1 - mn)
                    + __builtin_amdgcn_exp2f(l2 - mn) + __builtin_amdgcn_exp2f(l3 - mn);
          m2[rt][r] = mn;
        }
    }
    __syncthreads();   // all waves done reading Bt
    if (cc < 3) stage(cc + 1);
  }

  // merge the 16 lo-lanes per row; write per-(row,half) partials
#pragma unroll
  for (int rt = 0; rt < 2; ++rt)
#pragma unroll
    for (int r = 0; r < 4; ++r) {
      float m = m2[rt][r], s = s2[rt][r], p = pos[rt][r];
#pragma unroll
      for (int w = 1; w < 16; w <<= 1) {
        float mo = __shfl_xor(m, w), so = __shfl_xor(s, w);
        float mn = fmaxf(m, mo);
        s = s * __builtin_amdgcn_exp2f(m - mn) + so * __builtin_amdgcn_exp2f(mo - mn);
        m = mn;
        p = fmaxf(p, __shfl_xor(p, w));
      }
      if (lo == 0) {
        int row = rowbase + rt * 16 + hi * 4 + r;
        part[half * NB + row] = make_float2(m, s);
        posarr[half * NB + row] = p;
      }
    }
}

// Merge per-row halves -> sum(pos2 - lse2) -> accum[0]. 256 blocks x 256.
__global__ __launch_bounds__(256) void merge_k(const float2* __restrict__ part,
                                               const float* __restrict__ posarr,
                                               float* __restrict__ accum) {
  __shared__ float red[4];
  const int row = blockIdx.x * 256 + threadIdx.x;
  float2 p0 = part[row], p1 = part[NB + row];
  float m = fmaxf(p0.x, p1.x);
  float s = p0.y * __builtin_amdgcn_exp2f(p0.x - m) + p1.y * __builtin_amdgcn_exp2f(p1.x - m);
  s -= 24.0f * __builtin_amdgcn_exp2f(0.0f - m);   // 24 pad cols (logit2 == 0)
  s = fmaxf(s, 1e-30f);
  float lse2 = m + __builtin_amdgcn_logf(s);       // v_log_f32 = log2
  float p = fmaxf(posarr[row], posarr[NB + row]);
  float v = p - lse2;
#pragma unroll
  for (int w = 1; w < 64; w <<= 1) v += __shfl_xor(v, w);
  if ((threadIdx.x & 63) == 0) red[threadIdx.x >> 6] = v;
  __syncthreads();
  if (threadIdx.x == 0)
    atomicAdd(&accum[0], red[0] + red[1] + red[2] + red[3]);
}

// Dispersion: 256 blocks x 1 wave; (row-tile rt, col-quarter q); frag-major reads.
__global__ __launch_bounds__(64) void cider_disp(const short* __restrict__ mubf,
                                                 float2* __restrict__ dpart) {
  const int lane = threadIdx.x;
  const int lo = lane & 15, hi = lane >> 4;
  const int rt = blockIdx.x >> 2, q = blockIdx.x & 3;
  const char* mb = (const char*)mubf;

  bf16x8 a[4];
#pragma unroll
  for (int ks = 0; ks < 4; ++ks)
    a[ks] = *reinterpret_cast<const bf16x8*>(
        mb + (size_t)(rt >> 3) * 32768 + (rt & 7) * 4096 + ks * 1024 + lane * 16);

  int rowg[4];
#pragma unroll
  for (int r = 0; r < 4; ++r) rowg[r] = rt * 16 + hi * 4 + r;

  float m2[4], s2[4];
#pragma unroll
  for (int r = 0; r < 4; ++r) { m2[r] = -1e30f; s2[r] = 0.f; }

#pragma unroll 1
  for (int cc = 0; cc < 4; ++cc) {
    const int c0 = q * 256 + cc * 64;
    f32x4 acc[4];
#pragma unroll
    for (int f = 0; f < 4; ++f) acc[f] = f32x4{0.f, 0.f, 0.f, 0.f};
#pragma unroll
    for (int ks = 0; ks < 4; ++ks) {
#pragma unroll
      for (int f = 0; f < 4; ++f) {
        int Tb = (c0 >> 4) + f;
        bf16x8 b = *reinterpret_cast<const bf16x8*>(
            mb + (size_t)(Tb >> 3) * 32768 + (Tb & 7) * 4096 + ks * 1024 + lane * 16);
        acc[f] = __builtin_amdgcn_mfma_f32_16x16x32_bf16(a[ks], b, acc[f], 0, 0, 0);
      }
    }
#pragma unroll
    for (int r = 0; r < 4; ++r) {
      float l[4];
#pragma unroll
      for (int f = 0; f < 4; ++f) {
        int c = c0 + f * 16 + lo;
        l[f] = (c >= NCLS || c == rowg[r]) ? -1e30f : acc[f][r] * K2;
      }
      float cm = fmaxf(fmaxf(l[0], l[1]), fmaxf(l[2], l[3]));
      float mo = m2[r], mn = fmaxf(mo, cm);
      s2[r] = s2[r] * __builtin_amdgcn_exp2f(mo - mn)
            + __builtin_amdgcn_exp2f(l[0] - mn) + __builtin_amdgcn_exp2f(l[1] - mn)
            + __builtin_amdgcn_exp2f(l[2] - mn) + __builtin_amdgcn_exp2f(l[3] - mn);
      m2[r] = mn;
    }
  }

#pragma unroll
  for (int r = 0; r < 4; ++r) {
    float m = m2[r], s = s2[r];
#pragma unroll
    for (int w = 1; w < 16; w <<= 1) {
      float mo = __shfl_xor(m, w), so = __shfl_xor(s, w);
      float mn = fmaxf(m, mo);
      s = s * __builtin_amdgcn_exp2f(m - mn) + so * __builtin_amdgcn_exp2f(mo - mn);
      m = mn;
    }
    if (lo == 0) dpart[q * 1024 + rt * 16 + hi * 4 + r] = make_float2(m, s);
  }
}

// Final: merge disp quarters + combine losses. One block, 1024 threads.
__global__ __launch_bounds__(1024) void finalize_k(const float* __restrict__ accum,
                                                   const float2* __restrict__ dpart,
                                                   float* __restrict__ out) {
  __shared__ float red[16];
  const int row = threadIdx.x;
  float m = -1e30f, s = 0.f;
#pragma unroll
  for (int qq = 0; qq < 4; ++qq) {
    float2 p = dpart[qq * 1024 + row];
    float mn = fmaxf(m, p.x);
    s = s * __builtin_amdgcn_exp2f(m - mn) + p.y * __builtin_amdgcn_exp2f(p.x - mn);
    m = mn;
  }
  float v = 0.f;
  if (row < NCLS) v = m + __builtin_amdgcn_logf(fmaxf(s, 1e-30f));
#pragma unroll
  for (int w = 1; w < 64; w <<= 1) v += __shfl_xor(v, w);
  if ((row & 63) == 0) red[row >> 6] = v;
  __syncthreads();
  if (row == 0) {
    float t = 0.f;
#pragma unroll
    for (int i = 0; i < 16; ++i) t += red[i];
    float loss_comp = -(LN2 * accum[0] / (float)NB);
    float loss_dis = logf(1.0f / (float)(NCLS - 1)) + LN2 * t / (float)NCLS;
    out[0] = loss_dis + 2.0f * loss_comp;
  }
}

extern "C" void kernel_launch(void* const* d_in, const int* in_sizes, int n_in,
                              void* d_out, int out_size, void* d_ws, size_t ws_size,
                              hipStream_t stream) {
  const float* z = (const float*)d_in[0];
  const int* tgt = (const int*)d_in[1];
  const float* mu = (const float*)d_in[2];
  float* out = (float*)d_out;
  char* ws = (char*)d_ws;
  float*  accum  = (float*)ws;                         // 256 B
  short*  mubf   = (short*)(ws + 256);                 // 256 KB frag-major
  float2* part   = (float2*)(ws + 256 + 262144);       // 1 MB  (2 x 65536)
  float*  posarr = (float*)(ws + 256 + 262144 + 1048576);        // 512 KB
  float2* dpart  = (float2*)(ws + 256 + 262144 + 1048576 + 524288);  // 32 KB

  hipMemsetAsync(d_ws, 0, 256, stream);
  prep_mu<<<dim3(64), dim3(256), 0, stream>>>(mu, mubf);
  cider_comp<<<dim3(1024), dim3(256), 0, stream>>>(z, mubf, tgt, part, posarr);
  cider_disp<<<dim3(256), dim3(64), 0, stream>>>(mubf, dpart);
  merge_k<<<dim3(256), dim3(256), 0, stream>>>(part, posarr, accum);
  finalize_k<<<dim3(1), dim3(1024), 0, stream>>>(accum, dpart, out);
}

// Round 5
// 72.938 us; speedup vs baseline: 1.1703x; 1.1703x over previous
//
#include <hip/hip_runtime.h>
#include <math.h>

typedef __attribute__((ext_vector_type(4))) float f32x4;
typedef __attribute__((ext_vector_type(8))) short bf16x8;

#define NCLS  1000
#define DDIM  128
#define NB    65536
#define K2    14.426950408889634f   /* (1/T)*log2(e): base-2 logits */
#define LN2   0.6931471805599453f

__device__ inline short f2bf(float f) {
  union { float f; unsigned u; } x; x.f = f;
  unsigned r = (x.u + 0x7fffu + ((x.u >> 16) & 1u)) >> 16;  // RNE
  return (short)r;
}
__device__ inline void gll16(const void* g, void* l) {
  __builtin_amdgcn_global_load_lds(
      (const __attribute__((address_space(1))) unsigned int*)g,
      (__attribute__((address_space(3))) unsigned int*)l, 16, 0, 0);
}

// mu (f32 1000x128) -> bf16 FRAG-MAJOR, zero-padded to 1024 classes.
// byte(c,ks,khi) = (c>>7)*32768 + ((c>>4)&7)*4096 + ks*1024 + (khi*16+(c&15))*16
// Each MFMA B-fragment (16 cols x 32 k) is a contiguous lane-linear 1KB.
__global__ __launch_bounds__(256) void prep_mu(const float* __restrict__ mu,
                                               short* __restrict__ mubf) {
  int idx = blockIdx.x * 256 + threadIdx.x;   // 64 blocks -> 16384 16B units
  int c = idx >> 4, j = idx & 15;
  int ks = j >> 2, khi = j & 3;
  bf16x8 o = {0, 0, 0, 0, 0, 0, 0, 0};
  if (c < NCLS) {
    const float4* p = reinterpret_cast<const float4*>(mu + (size_t)c * DDIM + ks * 32 + khi * 8);
    float4 u0 = p[0], u1 = p[1];
    o[0] = f2bf(u0.x); o[1] = f2bf(u0.y); o[2] = f2bf(u0.z); o[3] = f2bf(u0.w);
    o[4] = f2bf(u1.x); o[5] = f2bf(u1.y); o[6] = f2bf(u1.z); o[7] = f2bf(u1.w);
  }
  size_t a16 = (size_t)(c >> 7) * 2048 + ((c >> 4) & 7) * 256 + ks * 64 + khi * 16 + (c & 15);
  *reinterpret_cast<bf16x8*>(mubf + a16 * 8) = o;
}

// Compactness: 512 blocks x 4 waves; wave = 32 rows x ALL 1024 cols (z read
// once). B double-buffered 2x16KB (64-col chunks, 16 iters, 1 barrier/iter).
// Frag-major LDS: ds_read = base + lane*16 + imm -> zero bank conflicts.
__global__ __launch_bounds__(256, 3) void cider_comp(
    const float* __restrict__ z, const short* __restrict__ mubf,
    const int* __restrict__ tgt, float* __restrict__ accum) {
  const int tid = threadIdx.x;
  const int wid = tid >> 6, lane = tid & 63;
  const int lo = lane & 15, hi = lane >> 4;
  const int rowbase = blockIdx.x * 128 + wid * 32;

  __shared__ __align__(16) char Bt[2][16384];
  const char* mb = (const char*)mubf;
  const int soff = wid * 1024 + lane * 16;

  // stage chunk 0 into buf 0 before the register prologue
  {
    const char* src = mb + soff;
    char* dst = &Bt[0][0] + wid * 1024;
#pragma unroll
    for (int i = 0; i < 4; ++i) gll16(src + i * 4096, dst + i * 4096);
  }

  // A fragments (scaled by K2) and targets
  bf16x8 a[2][4];
#pragma unroll
  for (int rt = 0; rt < 2; ++rt) {
    int row = rowbase + rt * 16 + lo;
    const float4* zp = reinterpret_cast<const float4*>(z + (size_t)row * DDIM);
#pragma unroll
    for (int ks = 0; ks < 4; ++ks) {
      float4 u0 = zp[ks * 8 + hi * 2];
      float4 u1 = zp[ks * 8 + hi * 2 + 1];
      bf16x8 s;
      s[0] = f2bf(u0.x * K2); s[1] = f2bf(u0.y * K2);
      s[2] = f2bf(u0.z * K2); s[3] = f2bf(u0.w * K2);
      s[4] = f2bf(u1.x * K2); s[5] = f2bf(u1.y * K2);
      s[6] = f2bf(u1.z * K2); s[7] = f2bf(u1.w * K2);
      a[rt][ks] = s;
    }
  }
  int t8[2][4];
#pragma unroll
  for (int rt = 0; rt < 2; ++rt)
#pragma unroll
    for (int r = 0; r < 4; ++r) t8[rt][r] = tgt[rowbase + rt * 16 + hi * 4 + r];

  float m2[2][4], s2[2][4], pos[2][4];
#pragma unroll
  for (int rt = 0; rt < 2; ++rt)
#pragma unroll
    for (int r = 0; r < 4; ++r) { m2[rt][r] = -1e30f; s2[rt][r] = 0.f; pos[rt][r] = -3.0e38f; }

#pragma unroll 1
  for (int cc = 0; cc < 16; ++cc) {
    const int p = cc & 1;
    __syncthreads();   // stage(cc) landed (barrier drains vmcnt); buf p^1 free
    if (cc < 15) {     // issue next-chunk DMA; flies under this iter's compute
      const char* src = mb + (cc + 1) * 16384 + soff;
      char* dst = &Bt[p ^ 1][0] + wid * 1024;
#pragma unroll
      for (int i = 0; i < 4; ++i) gll16(src + i * 4096, dst + i * 4096);
    }

    f32x4 acc[2][4];
#pragma unroll
    for (int rt = 0; rt < 2; ++rt)
#pragma unroll
      for (int f = 0; f < 4; ++f) acc[rt][f] = f32x4{0.f, 0.f, 0.f, 0.f};
#pragma unroll
    for (int ks = 0; ks < 4; ++ks) {
#pragma unroll
      for (int f = 0; f < 4; ++f) {
        bf16x8 b = *reinterpret_cast<const bf16x8*>(&Bt[p][0] + (f * 4 + ks) * 1024 + lane * 16);
        acc[0][f] = __builtin_amdgcn_mfma_f32_16x16x32_bf16(a[0][ks], b, acc[0][f], 0, 0, 0);
        acc[1][f] = __builtin_amdgcn_mfma_f32_16x16x32_bf16(a[1][ks], b, acc[1][f], 0, 0, 0);
      }
    }

    const int colb = cc * 64 + lo;
#pragma unroll
    for (int rt = 0; rt < 2; ++rt)
#pragma unroll
      for (int r = 0; r < 4; ++r) {
        float l0 = acc[rt][0][r], l1 = acc[rt][1][r];
        float l2 = acc[rt][2][r], l3 = acc[rt][3][r];
        int t = t8[rt][r];
        float pp = pos[rt][r];
        pp = (colb == t) ? l0 : pp;
        pp = (colb + 16 == t) ? l1 : pp;
        pp = (colb + 32 == t) ? l2 : pp;
        pp = (colb + 48 == t) ? l3 : pp;
        pos[rt][r] = pp;
        float cm = fmaxf(fmaxf(l0, l1), fmaxf(l2, l3));
        float mo = m2[rt][r], mn = fmaxf(mo, cm);
        s2[rt][r] = s2[rt][r] * __builtin_amdgcn_exp2f(mo - mn)
                  + __builtin_amdgcn_exp2f(l0 - mn) + __builtin_amdgcn_exp2f(l1 - mn)
                  + __builtin_amdgcn_exp2f(l2 - mn) + __builtin_amdgcn_exp2f(l3 - mn);
        m2[rt][r] = mn;
      }
  }

  // merge 16 lo-lanes per row; pad correction; sum(pos2 - lse2) per wave
  float vsum = 0.f;
#pragma unroll
  for (int rt = 0; rt < 2; ++rt)
#pragma unroll
    for (int r = 0; r < 4; ++r) {
      float m = m2[rt][r], s = s2[rt][r], pp = pos[rt][r];
#pragma unroll
      for (int w = 1; w < 16; w <<= 1) {
        float mo = __shfl_xor(m, w), so = __shfl_xor(s, w);
        float mn = fmaxf(m, mo);
        s = s * __builtin_amdgcn_exp2f(m - mn) + so * __builtin_amdgcn_exp2f(mo - mn);
        m = mn;
        pp = fmaxf(pp, __shfl_xor(pp, w));
      }
      if (lo == 0) {
        s -= 24.0f * __builtin_amdgcn_exp2f(0.0f - m);  // 24 pad cols, logit2==0
        s = fmaxf(s, 1e-30f);
        float lse2 = m + __builtin_amdgcn_logf(s);      // v_log_f32 = log2
        vsum += pp - lse2;
      }
    }
#pragma unroll
  for (int w = 1; w < 64; w <<= 1) vsum += __shfl_xor(vsum, w);
  if (lane == 0) atomicAdd(&accum[0], vsum);
}

// Dispersion: 256 blocks x 1 wave; (row-tile rt, col-quarter q); frag-major L2 reads.
__global__ __launch_bounds__(64) void cider_disp(const short* __restrict__ mubf,
                                                 float2* __restrict__ dpart) {
  const int lane = threadIdx.x;
  const int lo = lane & 15, hi = lane >> 4;
  const int rt = blockIdx.x >> 2, q = blockIdx.x & 3;
  const char* mb = (const char*)mubf;

  bf16x8 a[4];
#pragma unroll
  for (int ks = 0; ks < 4; ++ks)
    a[ks] = *reinterpret_cast<const bf16x8*>(
        mb + (size_t)(rt >> 3) * 32768 + (rt & 7) * 4096 + ks * 1024 + lane * 16);

  int rowg[4];
#pragma unroll
  for (int r = 0; r < 4; ++r) rowg[r] = rt * 16 + hi * 4 + r;

  float m2[4], s2[4];
#pragma unroll
  for (int r = 0; r < 4; ++r) { m2[r] = -1e30f; s2[r] = 0.f; }

#pragma unroll 1
  for (int cc = 0; cc < 4; ++cc) {
    const int c0 = q * 256 + cc * 64;
    f32x4 acc[4];
#pragma unroll
    for (int f = 0; f < 4; ++f) acc[f] = f32x4{0.f, 0.f, 0.f, 0.f};
#pragma unroll
    for (int ks = 0; ks < 4; ++ks) {
#pragma unroll
      for (int f = 0; f < 4; ++f) {
        int Tb = (c0 >> 4) + f;
        bf16x8 b = *reinterpret_cast<const bf16x8*>(
            mb + (size_t)(Tb >> 3) * 32768 + (Tb & 7) * 4096 + ks * 1024 + lane * 16);
        acc[f] = __builtin_amdgcn_mfma_f32_16x16x32_bf16(a[ks], b, acc[f], 0, 0, 0);
      }
    }
#pragma unroll
    for (int r = 0; r < 4; ++r) {
      float l[4];
#pragma unroll
      for (int f = 0; f < 4; ++f) {
        int c = c0 + f * 16 + lo;
        l[f] = (c >= NCLS || c == rowg[r]) ? -1e30f : acc[f][r] * K2;
      }
      float cm = fmaxf(fmaxf(l[0], l[1]), fmaxf(l[2], l[3]));
      float mo = m2[r], mn = fmaxf(mo, cm);
      s2[r] = s2[r] * __builtin_amdgcn_exp2f(mo - mn)
            + __builtin_amdgcn_exp2f(l[0] - mn) + __builtin_amdgcn_exp2f(l[1] - mn)
            + __builtin_amdgcn_exp2f(l[2] - mn) + __builtin_amdgcn_exp2f(l[3] - mn);
      m2[r] = mn;
    }
  }

#pragma unroll
  for (int r = 0; r < 4; ++r) {
    float m = m2[r], s = s2[r];
#pragma unroll
    for (int w = 1; w < 16; w <<= 1) {
      float mo = __shfl_xor(m, w), so = __shfl_xor(s, w);
      float mn = fmaxf(m, mo);
      s = s * __builtin_amdgcn_exp2f(m - mn) + so * __builtin_amdgcn_exp2f(mo - mn);
      m = mn;
    }
    if (lo == 0) dpart[q * 1024 + rt * 16 + hi * 4 + r] = make_float2(m, s);
  }
}

// Final: merge disp quarters + combine losses. One block, 1024 threads.
__global__ __launch_bounds__(1024) void finalize_k(const float* __restrict__ accum,
                                                   const float2* __restrict__ dpart,
                                                   float* __restrict__ out) {
  __shared__ float red[16];
  const int row = threadIdx.x;
  float m = -1e30f, s = 0.f;
#pragma unroll
  for (int qq = 0; qq < 4; ++qq) {
    float2 p = dpart[qq * 1024 + row];
    float mn = fmaxf(m, p.x);
    s = s * __builtin_amdgcn_exp2f(m - mn) + p.y * __builtin_amdgcn_exp2f(p.x - mn);
    m = mn;
  }
  float v = 0.f;
  if (row < NCLS) v = m + __builtin_amdgcn_logf(fmaxf(s, 1e-30f));
#pragma unroll
  for (int w = 1; w < 64; w <<= 1) v += __shfl_xor(v, w);
  if ((row & 63) == 0) red[row >> 6] = v;
  __syncthreads();
  if (row == 0) {
    float t = 0.f;
#pragma unroll
    for (int i = 0; i < 16; ++i) t += red[i];
    float loss_comp = -(LN2 * accum[0] / (float)NB);
    float loss_dis = logf(1.0f / (float)(NCLS - 1)) + LN2 * t / (float)NCLS;
    out[0] = loss_dis + 2.0f * loss_comp;
  }
}

extern "C" void kernel_launch(void* const* d_in, const int* in_sizes, int n_in,
                              void* d_out, int out_size, void* d_ws, size_t ws_size,
                              hipStream_t stream) {
  const float* z = (const float*)d_in[0];
  const int* tgt = (const int*)d_in[1];
  const float* mu = (const float*)d_in[2];
  float* out = (float*)d_out;
  char* ws = (char*)d_ws;
  float*  accum = (float*)ws;                      // 256 B
  short*  mubf  = (short*)(ws + 256);              // 256 KB frag-major
  float2* dpart = (float2*)(ws + 256 + 262144);    // 32 KB

  hipMemsetAsync(d_ws, 0, 256, stream);
  prep_mu<<<dim3(64), dim3(256), 0, stream>>>(mu, mubf);
  cider_comp<<<dim3(512), dim3(256), 0, stream>>>(z, mubf, tgt, accum);
  cider_disp<<<dim3(256), dim3(64), 0, stream>>>(mubf, dpart);
  finalize_k<<<dim3(1), dim3(1024), 0, stream>>>(accum, dpart, out);
}